// Round 1
// 329.604 us; speedup vs baseline: 1.0083x; 1.0083x over previous
//
#include <hip/hip_runtime.h>

// Problem constants (from reference): B=64, N=883, TN=16, T=12, TOD=288
#define NBATCH 64
#define NN     883
#define TN     16
#define TT     12
#define TOD    288

__device__ __forceinline__ float fastdiv(float a, float b) {
    return a * __builtin_amdgcn_rcpf(b);   // v_rcp_f32: ~1 ulp*2^-12 rel err, fine at 2% tol
}

__device__ __forceinline__ float rsum16(float v) {
#pragma unroll
    for (int m = 1; m < 16; m <<= 1) v += __shfl_xor(v, m, 16);
    return v;
}
__device__ __forceinline__ float rmax16(float v) {
#pragma unroll
    for (int m = 1; m < 16; m <<= 1) v = fmaxf(v, __shfl_xor(v, m, 16));
    return v;
}

// Grid layout: n-major. blockIdx = n*4 + q ; block covers b = q*16 + grp for a
// single n. The 4 consecutive blocks of one n read their 64 K/V chunks (768 B
// each) from ONE contiguous 221 KB window of k_bank/v_bank -> DRAM row-buffer
// locality, instead of hopping the full 195 MB array at 221 KB stride (b-major).
__global__ __launch_bounds__(256) void modeatt_kernel(
    const float* __restrict__ enc, const int* __restrict__ xmark,
    const float* __restrict__ dec, const float* __restrict__ kbank,
    const float* __restrict__ vbank, const float* __restrict__ attw,
    const float* __restrict__ attb, float* __restrict__ out)
{
    const int tid  = threadIdx.x;
    const int grp  = tid >> 4;        // 16 pairs per 256-thread block
    const int lane = tid & 15;        // key index y within the pair
    const int n = blockIdx.x >> 2;    // block-uniform: attw/attb scalarize
    const int q = blockIdx.x & 3;
    const int b = (q << 4) | grp;
    const int pair = b * NN + n;
    const int t = xmark[b * 2];       // x_mark_enc[b,0,0]

    // ---- issue ALL global loads up front; compiler emits partial vmcnt waits
    const long kvoff = ((long)(n * TOD + t) * TN + lane) * TT;
    const float4* kp = (const float4*)(kbank + kvoff);
    const float4* vp = (const float4*)(vbank + kvoff);
    const float4* qp = (const float4*)(enc + pair * TT);

    float4 k0 = kp[0], k1 = kp[1], k2 = kp[2];
    float4 v0 = vp[0], v1 = vp[1], v2 = vp[2];
    float4 q0 = qp[0], q1 = qp[1], q2 = qp[2];

    float4 dq = make_float4(0.f, 0.f, 0.f, 0.f);
    if (lane < 3) dq = ((const float4*)(dec + pair * TT))[lane];

    const float awy  = attw[n * 17 + lane];
    const float aw16 = attw[n * 17 + 16];
    const float bias = attb[n];

    // ---- distance for this lane's key
    float qv[TT] = { q0.x, q0.y, q0.z, q0.w, q1.x, q1.y, q1.z, q1.w, q2.x, q2.y, q2.z, q2.w };
    float kv[TT] = { k0.x, k0.y, k0.z, k0.w, k1.x, k1.y, k1.z, k1.w, k2.x, k2.y, k2.z, k2.w };
    float s = 0.f;
#pragma unroll
    for (int d = 0; d < TT; ++d) { float df = qv[d] - kv[d]; s += df * df; }
    const float dist = sqrtf(s);

    // ---- score 1: stats over the 16 bank keys (two-pass variance, ddof=1)
    const float S1    = rsum16(dist);
    const float mean1 = S1 * (1.0f / 16.0f);
    const float dev   = dist - mean1;
    const float Sdev2 = rsum16(dev * dev);
    const float std1  = sqrtf(Sdev2 * (1.0f / 15.0f)) + 1e-6f;
    const float sc1   = fastdiv(mean1 - dist, std1) * 10.0f;

    const float m1  = rmax16(sc1);
    const float e1  = __expf(sc1 - m1);
    const float Z1  = rsum16(e1);
    const float att = fastdiv(e1, Z1);

    // att_out[d] = sum_y att_y * V[y][d]  (butterfly leaves the sum in all lanes)
    float v[TT] = { v0.x, v0.y, v0.z, v0.w, v1.x, v1.y, v1.z, v1.w, v2.x, v2.y, v2.z, v2.w };
    float ao[TT];
#pragma unroll
    for (int d = 0; d < TT; ++d) ao[d] = att * v[d];
#pragma unroll
    for (int m = 1; m < 16; m <<= 1) {
#pragma unroll
        for (int d = 0; d < TT; ++d) ao[d] += __shfl_xor(ao[d], m, 16);
    }

    // ---- score 2: 17 keys, key #17 is Q+0.1 -> constant distance sqrt(12*0.01)
    const float d17   = 0.34641016151377546f;
    const float mean2 = (S1 + d17) * (1.0f / 17.0f);
    const float dm    = mean1 - mean2;
    const float dd    = d17 - mean2;
    // sum over 17 of (d - mean2)^2 = Sdev2 + 16*dm^2 + dd^2 ; ddof=1 -> /16
    const float var2  = (Sdev2 + 16.0f * dm * dm + dd * dd) * (1.0f / 16.0f);
    const float std2  = sqrtf(var2) + 1e-6f;
    const float rstd2 = __builtin_amdgcn_rcpf(std2);
    const float sc2   = (mean2 - dist) * rstd2 * 10.0f;
    const float sc17  = (mean2 - d17) * rstd2 * 10.0f;

    const float m2  = fmaxf(rmax16(sc2), sc17);
    const float e2  = __expf(sc2 - m2);
    const float e17 = __expf(sc17 - m2);
    const float Z2  = rsum16(e2) + e17;

    const float num = rsum16(e2 * awy) + e17 * aw16;
    const float w   = fastdiv(num, Z2) + bias;

    // ---- blend + store: lanes 0..2 each write one float4 (48 B per pair)
    if (lane < 3) {
        const float ow = 1.0f - w;
        float4 o;
        o.x = ow * ao[lane * 4 + 0] + w * dq.x;
        o.y = ow * ao[lane * 4 + 1] + w * dq.y;
        o.z = ow * ao[lane * 4 + 2] + w * dq.z;
        o.w = ow * ao[lane * 4 + 3] + w * dq.w;
        ((float4*)(out + pair * TT))[lane] = o;
    }
}

extern "C" void kernel_launch(void* const* d_in, const int* in_sizes, int n_in,
                              void* d_out, int out_size, void* d_ws, size_t ws_size,
                              hipStream_t stream) {
    const float* enc = (const float*)d_in[0];
    const int*   xm  = (const int*)d_in[1];
    const float* dec = (const float*)d_in[2];
    const float* kb  = (const float*)d_in[3];
    const float* vb  = (const float*)d_in[4];
    const float* aw  = (const float*)d_in[5];
    const float* ab  = (const float*)d_in[6];
    float* out = (float*)d_out;

    dim3 grid(NN * 4);                // 3532 blocks: n-major, 4 b-quads per n
    modeatt_kernel<<<grid, 256, 0, stream>>>(enc, xm, dec, kb, vb, aw, ab, out);
}